// Round 12
// baseline (794.220 us; speedup 1.0000x reference)
//
#include <hip/hip_runtime.h>
#include <hip/hip_bf16.h>
#include <math.h>

#define D_   512
#define DI_  1024
#define S_   16
#define R_   32
#define KC_  4
#define NL_  6
#define B_   4
#define L_   1024
#define BL_  (B_*L_)
#define NC_  64
#define CL_  (L_/NC_)
#define BDI_ (B_*DI_)
#define LOG2E 1.44269504f
#define SKX  8
#define SKO  4

typedef __hip_bfloat16 bf16;
typedef __attribute__((ext_vector_type(8))) short bf16x8;
typedef __attribute__((ext_vector_type(4))) float f32x4;
typedef unsigned short u16;

// q / hini layout: [s][c][b*DI+d]  (fast axis d -> coalesced)
#define QIDX(s, c, bd) (((size_t)(s) * NC_ + (c)) * BDI_ + (bd))

__device__ __forceinline__ float b2f(u16 u) {
  union { unsigned int i; float f; } x; x.i = ((unsigned int)u) << 16; return x.f;
}

__device__ __forceinline__ float softplus_f(float v) {
  float e = __expf(-fabsf(v));
  return fmaxf(v, 0.f) + __logf(1.f + e);
}

__device__ __forceinline__ void gload16(const void* g, void* l) {
  __builtin_amdgcn_global_load_lds((const __attribute__((address_space(1))) void*)g,
                                   (__attribute__((address_space(3))) void*)l, 16, 0, 0);
}

// ---------------- one-shot setup: weight converts + A-table precompute ----------------
#define N1_  (NL_*2*DI_*D_)
#define N2_  (N1_ + NL_*D_*DI_)
#define N3_  (N2_ + NL_*128*DI_)
#define N3B_ (N3_ + NL_*DI_*R_)
#define N4_  (N3B_ + NL_*DI_)
__global__ void setup_k(const float* __restrict__ in_w, const float* __restrict__ out_w,
                        const float* __restrict__ xp_w, const float* __restrict__ dt_w,
                        const float* __restrict__ A_log,
                        bf16* __restrict__ inw_b, bf16* __restrict__ outw_b,
                        bf16* __restrict__ xpw_b, bf16* __restrict__ dtw_b,
                        float* __restrict__ an2b, float* __restrict__ ff,
                        float* __restrict__ an2f) {
  for (int i = blockIdx.x * blockDim.x + threadIdx.x; i < N4_; i += gridDim.x * blockDim.x) {
    if (i < N1_) {
      inw_b[i] = __float2bfloat16(in_w[i]);
    } else if (i < N2_) {
      int j = i - N1_;
      outw_b[j] = __float2bfloat16(out_w[j]);
    } else if (i < N3_) {
      int j = i - N2_;
      int c = j & (DI_ - 1);
      int r = (j >> 10) & 127;
      int l = j >> 17;
      float v = (r < 64) ? xp_w[((size_t)l * 64 + r) * DI_ + c] : 0.f;
      xpw_b[j] = __float2bfloat16(v);
    } else if (i < N3B_) {
      int j = i - N3_;
      dtw_b[j] = __float2bfloat16(dt_w[j]);
    } else {
      int j = i - N3B_;                          // j = l*DI + d
      int d = j & (DI_ - 1);
      int l = j >> 10;
      float base = -expf(A_log[(size_t)j * S_]) * LOG2E;
      bool fast = true;
      #pragma unroll
      for (int s = 0; s < S_; ++s) {
        float a = -expf(A_log[(size_t)j * S_ + s]) * LOG2E;
        an2f[((size_t)l * S_ + s) * DI_ + d] = a;
        fast = fast && (fabsf(a - (float)(s + 1) * base) <= 1e-5f * fabsf(a));
      }
      an2b[j] = base;
      ff[j] = fast ? 1.f : 0.f;
    }
  }
}

// ---------------- residual add (+ bf16 split-K reduce) + LayerNorm -> bf16 ----------------
__global__ __launch_bounds__(128) void addln_k(
    const float* __restrict__ x0, const u16* __restrict__ parts,
    float* __restrict__ resid, const float* __restrict__ w, const float* __restrict__ b,
    bf16* __restrict__ hn, int first)
{
  __shared__ float red[4];
  const int row = blockIdx.x, t = threadIdx.x;
  const int lane = t & 63, wv = t >> 6;
  float4 v;
  if (first) {
    v = *(const float4*)(x0 + (size_t)row * D_ + t * 4);
  } else {
    const size_t ps = (size_t)BL_ * D_;
    const size_t o = (size_t)row * D_ + t * 4;
    v.x = 0.f; v.y = 0.f; v.z = 0.f; v.w = 0.f;
    #pragma unroll
    for (int p = 0; p < SKO; ++p) {
      ushort4 q = *(const ushort4*)(parts + p * ps + o);
      v.x += b2f(q.x); v.y += b2f(q.y); v.z += b2f(q.z); v.w += b2f(q.w);
    }
    float4 r = *(const float4*)(resid + o);
    v.x += r.x; v.y += r.y; v.z += r.z; v.w += r.w;
  }
  *(float4*)(resid + (size_t)row * D_ + t * 4) = v;
  float s = v.x + v.y + v.z + v.w;
  float ss = v.x*v.x + v.y*v.y + v.z*v.z + v.w*v.w;
  #pragma unroll
  for (int o = 32; o > 0; o >>= 1) { s += __shfl_xor(s, o); ss += __shfl_xor(ss, o); }
  if (lane == 0) { red[wv * 2] = s; red[wv * 2 + 1] = ss; }
  __syncthreads();
  float S = red[0] + red[2], SS = red[1] + red[3];
  float m = S * (1.f / D_), var = SS * (1.f / D_) - m * m;
  float rs = rsqrtf(var + 1e-5f);
  float4 w4 = *(const float4*)(w + t * 4);
  float4 b4 = *(const float4*)(b + t * 4);
  bf16* o = hn + (size_t)row * D_ + t * 4;
  o[0] = __float2bfloat16((v.x - m) * rs * w4.x + b4.x);
  o[1] = __float2bfloat16((v.y - m) * rs * w4.y + b4.y);
  o[2] = __float2bfloat16((v.z - m) * rs * w4.z + b4.z);
  o[3] = __float2bfloat16((v.w - m) * rs * w4.w + b4.w);
}

// ---------------- bf16 MFMA GEMM, C[m,n] = sum_k A[m,k]*B[n,k] ----------------
// Split-K via gridDim.z.
// epi: 1 = bf16 partial store [kz][M][Nact]; 2 = softplus(v+bias[col]) bf16; 3 = bf16 dense
__global__ __launch_bounds__(256) void gemm_bt(
    const bf16* __restrict__ A, int lda,
    const bf16* __restrict__ B, int ldb,
    bf16* __restrict__ Cb, const float* __restrict__ bias,
    int K, int Nact, int M, int epi)
{
  __shared__ __align__(16) bf16 As[128 * 32];
  __shared__ __align__(16) bf16 Bs[128 * 32];
  const int tid = threadIdx.x;
  const int wave = tid >> 6, lane = tid & 63;
  const int bm = blockIdx.x * 128, bn = blockIdx.y * 128;
  const int kz = blockIdx.z;
  const int Kc = K / gridDim.z;
  const int k0 = kz * Kc, k1 = k0 + Kc;
  const int wr = (wave >> 1) << 6, wc = (wave & 1) << 6;
  const int srow = lane >> 2, scg = lane & 3;
  const int rA = lane & 15, kq = (lane >> 4) << 3;
  f32x4 acc[4][4] = {};
  for (int kt = k0; kt < k1; kt += 32) {
    __syncthreads();
    #pragma unroll
    for (int p = 0; p < 2; ++p) {
      int chunk = wave * 2 + p;
      int row = (chunk << 4) + srow;
      gload16(A + (size_t)(bm + row) * lda + kt + scg * 8, &As[chunk * 512]);
      gload16(B + (size_t)(bn + row) * ldb + kt + scg * 8, &Bs[chunk * 512]);
    }
    __syncthreads();
    bf16x8 af[4], bq[4];
    #pragma unroll
    for (int m = 0; m < 4; ++m) af[m] = *(const bf16x8*)&As[(wr + m * 16 + rA) * 32 + kq];
    #pragma unroll
    for (int n = 0; n < 4; ++n) bq[n] = *(const bf16x8*)&Bs[(wc + n * 16 + rA) * 32 + kq];
    #pragma unroll
    for (int m = 0; m < 4; ++m)
      #pragma unroll
      for (int n = 0; n < 4; ++n)
        acc[m][n] = __builtin_amdgcn_mfma_f32_16x16x32_bf16(af[m], bq[n], acc[m][n], 0, 0, 0);
  }
  const int cr = (lane >> 4) << 2, cc = lane & 15;
  const size_t pbase = (epi == 1) ? (size_t)kz * M * Nact : 0;
  #pragma unroll
  for (int m = 0; m < 4; ++m)
    #pragma unroll
    for (int n = 0; n < 4; ++n) {
      int col = bn + wc + n * 16 + cc;
      if (col >= Nact) continue;
      #pragma unroll
      for (int j = 0; j < 4; ++j) {
        size_t row = (size_t)(bm + wr + m * 16 + cr + j);
        float v = acc[m][n][j];
        if (epi == 2) v = softplus_f(v + bias[col]);
        Cb[pbase + row * Nact + col] = __float2bfloat16(v);
      }
    }
}

// ---------------- reduce x_proj bf16 split-K partials -> dbc f32 + dbcb bf16 ----------------
__global__ __launch_bounds__(256) void redx_k(
    const u16* __restrict__ part, float* __restrict__ dbc, bf16* __restrict__ dbcb)
{
  int i = blockIdx.x * 256 + threadIdx.x;      // BL*64 threads
  const size_t ps = (size_t)BL_ * 64;
  float v = 0.f;
  #pragma unroll
  for (int p = 0; p < SKX; ++p) v += b2f(part[p * ps + i]);
  dbc[i] = v;
  dbcb[i] = __float2bfloat16(v);
}

// ---------------- causal conv (K=4) + SiLU, bf16 in/out, 8 chans/thread ----------------
__global__ __launch_bounds__(256) void conv_silu_k(
    const u16* __restrict__ xz, const float* __restrict__ cw, const float* __restrict__ cb,
    bf16* __restrict__ xcb)
{
  int g = blockIdx.x * 256 + threadIdx.x;     // BL*DI/8 threads
  int dq = g & (DI_ / 8 - 1);
  int bl = g >> 7;
  int l = bl & (L_ - 1), b = bl >> 10;
  int d = dq * 8;
  float a[8], wv[8][KC_];
  #pragma unroll
  for (int e = 0; e < 8; ++e) {
    float4 w4 = *(const float4*)(cw + (d + e) * KC_);
    wv[e][0] = w4.x; wv[e][1] = w4.y; wv[e][2] = w4.z; wv[e][3] = w4.w;
    a[e] = cb[d + e];
  }
  #pragma unroll
  for (int k = 0; k < KC_; ++k) {
    int lt = l + k - 3;
    if (lt < 0) continue;
    bf16x8 xv = *(const bf16x8*)(xz + (size_t)(b * L_ + lt) * (2 * DI_) + d);
    #pragma unroll
    for (int e = 0; e < 8; ++e) a[e] += b2f((u16)xv[e]) * wv[e][k];
  }
  bf16 o8[8];
  #pragma unroll
  for (int e = 0; e < 8; ++e) {
    float v = a[e] / (1.f + __expf(-a[e]));
    o8[e] = __float2bfloat16(v);
  }
  *(bf16x8*)(xcb + (size_t)bl * DI_ + d) = *(const bf16x8*)o8;
}

// ---------------- chunked selective scan (3 kernels), CL=16 ----------------
// fast path: dA[s] = E^(s+1), E = exp2(dt*an2b). Generic per-s fallback stays correct.

// pass A: local scan with h0=0 -> sumdt, q(bf16). dt read from dtb (MFMA-computed).
__global__ __launch_bounds__(256) void scanA_k(
    const u16* __restrict__ dt, const u16* __restrict__ x, const float* __restrict__ dbc,
    const float* __restrict__ an2b, const float* __restrict__ ff,
    const float* __restrict__ A_log,
    float* __restrict__ sumdt, bf16* __restrict__ q)
{
  __shared__ float BS[CL_ * 16];                 // B rows of this chunk
  const int tid = threadIdx.x;
  int g = blockIdx.x * 256 + tid;                // NC*B*DI threads
  int d = g & (DI_ - 1);
  int cb = g >> 10;
  int b = cb & (B_ - 1);
  int c = cb >> 2;
  {
    int step = tid >> 4, off = tid & 15;         // 256 = CL*16
    BS[tid] = dbc[((size_t)(b * L_ + c * CL_ + step)) * 64 + R_ + off];
  }
  const float An2b = an2b[d];
  const bool fast = (ff[d] != 0.f);
  __syncthreads();
  float h[S_] = {};
  float sdt = 0.f;
  const size_t base = ((size_t)b * L_ + c * CL_) * DI_ + d;
  float cdt = b2f(dt[base]), cx = b2f(x[base]);
  for (int i = 0; i < CL_; ++i) {
    const int ip = (i + 1 < CL_) ? i + 1 : i;
    float ndt = b2f(dt[base + (size_t)ip * DI_]);
    float nx  = b2f(x[base + (size_t)ip * DI_]);
    float u = cdt * cx;
    sdt += cdt;
    float Bv[S_];
    *(float4*)&Bv[0]  = *(const float4*)&BS[i * 16 + 0];
    *(float4*)&Bv[4]  = *(const float4*)&BS[i * 16 + 4];
    *(float4*)&Bv[8]  = *(const float4*)&BS[i * 16 + 8];
    *(float4*)&Bv[12] = *(const float4*)&BS[i * 16 + 12];
    float da[S_];
    if (fast) {
      float E1 = exp2f(cdt * An2b);
      float E2 = E1 * E1;
      float E4 = E2 * E2;
      da[0] = E1; da[1] = E2; da[2] = E2 * E1; da[3] = E4;
      #pragma unroll
      for (int s = 4; s < S_; ++s) da[s] = da[s - 4] * E4;
    } else {
      #pragma unroll
      for (int s = 0; s < S_; ++s)
        da[s] = exp2f(cdt * (-expf(A_log[(size_t)d * S_ + s]) * LOG2E));
    }
    #pragma unroll
    for (int s = 0; s < S_; ++s) h[s] = da[s] * h[s] + u * Bv[s];
    cdt = ndt; cx = nx;
  }
  int bd = b * DI_ + d;
  sumdt[(size_t)c * BDI_ + bd] = sdt;
  #pragma unroll
  for (int s = 0; s < S_; ++s) q[QIDX(s, c, bd)] = __float2bfloat16(h[s]);
}

// pass B: per (s,bd): propagate chunk boundary states (bf16 q/hi); an2f coalesced
__global__ __launch_bounds__(256) void scanB_k(
    const float* __restrict__ sumdt, const u16* __restrict__ q,
    const float* __restrict__ an2f, bf16* __restrict__ hi)
{
  int g = blockIdx.x * 256 + threadIdx.x;        // B*DI*S threads: g = s*BDI + bd
  int s = g >> 12;
  int bd = g & (BDI_ - 1);
  int d = bd & (DI_ - 1);
  float An2 = an2f[(size_t)s * DI_ + d];
  float h = 0.f;
  float sd = sumdt[bd];
  float qq = b2f(q[(size_t)s * NC_ * BDI_ + bd]);
  for (int c = 0; c < NC_; ++c) {
    float sdn = sd, qn = qq;
    if (c + 1 < NC_) {
      sdn = sumdt[(size_t)(c + 1) * BDI_ + bd];
      qn  = b2f(q[QIDX(s, c + 1, bd)]);
    }
    hi[QIDX(s, c, bd)] = __float2bfloat16(h);
    h = exp2f(An2 * sd) * h + qq;
    sd = sdn; qq = qn;
  }
}

// pass C: rescan with correct init; fuse y = (scan + x*Dp) * silu(z) -> bf16
__global__ __launch_bounds__(256) void scanC_k(
    const u16* __restrict__ dt, const u16* __restrict__ x, const float* __restrict__ dbc,
    const float* __restrict__ A_log, const float* __restrict__ an2b,
    const float* __restrict__ ff, const float* __restrict__ Dp, const u16* __restrict__ xz,
    const u16* __restrict__ hi, bf16* __restrict__ y)
{
  __shared__ float BCS[CL_ * 32];                // B+C rows of this chunk
  const int tid = threadIdx.x;
  int g = blockIdx.x * 256 + tid;
  int d = g & (DI_ - 1);
  int cb = g >> 10;
  int b = cb & (B_ - 1);
  int c = cb >> 2;
  {
    int f = tid * 2;                             // 512 floats = CL*32
    int step = f >> 5, off = f & 31;
    float2 v = *(const float2*)(dbc + ((size_t)(b * L_ + c * CL_ + step)) * 64 + R_ + off);
    BCS[f] = v.x; BCS[f + 1] = v.y;
  }
  const float An2b = an2b[d];
  const bool fast = (ff[d] != 0.f);
  int bd = b * DI_ + d;
  float h[S_];
  #pragma unroll
  for (int s = 0; s < S_; ++s) h[s] = b2f(hi[QIDX(s, c, bd)]);
  __syncthreads();
  float dpv = Dp[d];
  const size_t rid0 = (size_t)b * L_ + c * CL_;
  const size_t base = rid0 * DI_ + d;
  float cdt = b2f(dt[base]), cx = b2f(x[base]);
  float cz = b2f(xz[rid0 * (2 * DI_) + DI_ + d]);
  float Ecur = exp2f(cdt * An2b);
  for (int i = 0; i < CL_; ++i) {
    const int ip = (i + 1 < CL_) ? i + 1 : i;
    float ndt = b2f(dt[base + (size_t)ip * DI_]);
    float nx  = b2f(x[base + (size_t)ip * DI_]);
    float nz  = b2f(xz[(rid0 + ip) * (2 * DI_) + DI_ + d]);
    float Enext = exp2f(ndt * An2b);             // next boundary exp, issued early
    float u = cdt * cx;
    float Bv[S_], Cv[S_];
    *(float4*)&Bv[0]  = *(const float4*)&BCS[i * 32 + 0];
    *(float4*)&Bv[4]  = *(const float4*)&BCS[i * 32 + 4];
    *(float4*)&Bv[8]  = *(const float4*)&BCS[i * 32 + 8];
    *(float4*)&Bv[12] = *(const float4*)&BCS[i * 32 + 12];
    *(float4*)&Cv[0]  = *(const float4*)&BCS[i * 32 + 16];
    *(float4*)&Cv[4]  = *(const float4*)&BCS[i * 32 + 20];
    *(float4*)&Cv[8]  = *(const float4*)&BCS[i * 32 + 24];
    *(float4*)&Cv[12] = *(const float4*)&BCS[i * 32 + 28];
    float da[S_];
    if (fast) {
      float E1 = Ecur;
      float E2 = E1 * E1;
      float E4 = E2 * E2;
      da[0] = E1; da[1] = E2; da[2] = E2 * E1; da[3] = E4;
      #pragma unroll
      for (int s = 4; s < S_; ++s) da[s] = da[s - 4] * E4;
    } else {
      #pragma unroll
      for (int s = 0; s < S_; ++s)
        da[s] = exp2f(cdt * (-expf(A_log[(size_t)d * S_ + s]) * LOG2E));
    }
    float acc = 0.f;
    #pragma unroll
    for (int s = 0; s < S_; ++s) {
      h[s] = da[s] * h[s] + u * Bv[s];
      acc += h[s] * Cv[s];
    }
    acc += cx * dpv;
    acc *= cz / (1.f + __expf(-cz));
    y[(rid0 + i) * DI_ + d] = __float2bfloat16(acc);
    cdt = ndt; cx = nx; cz = nz; Ecur = Enext;
  }
}

// ---------------- final: reduce out partials + resid, LN(normf), LN(after), olens ----------------
__global__ __launch_bounds__(128) void final_k(
    const u16* __restrict__ parts, const float* __restrict__ res,
    const float* __restrict__ fw, const float* __restrict__ fb,
    const float* __restrict__ aw, const float* __restrict__ ab,
    const int* __restrict__ ilens, float* __restrict__ out, int outN)
{
  __shared__ float red[4];
  const int row = blockIdx.x, t = threadIdx.x;
  const int lane = t & 63, wv = t >> 6;
  const size_t ps = (size_t)BL_ * D_;
  const size_t o0 = (size_t)row * D_ + t * 4;
  float4 v; v.x = 0.f; v.y = 0.f; v.z = 0.f; v.w = 0.f;
  #pragma unroll
  for (int p = 0; p < SKO; ++p) {
    ushort4 q = *(const ushort4*)(parts + p * ps + o0);
    v.x += b2f(q.x); v.y += b2f(q.y); v.z += b2f(q.z); v.w += b2f(q.w);
  }
  float4 r = *(const float4*)(res + o0);
  v.x += r.x; v.y += r.y; v.z += r.z; v.w += r.w;
  float s = v.x + v.y + v.z + v.w;
  float ss = v.x*v.x + v.y*v.y + v.z*v.z + v.w*v.w;
  #pragma unroll
  for (int o = 32; o > 0; o >>= 1) { s += __shfl_xor(s, o); ss += __shfl_xor(ss, o); }
  if (lane == 0) { red[wv * 2] = s; red[wv * 2 + 1] = ss; }
  __syncthreads();
  float S = red[0] + red[2], SS = red[1] + red[3];
  float m = S * (1.f / D_), var = SS * (1.f / D_) - m * m;
  float rs = rsqrtf(var + 1e-5f);
  float4 w4 = *(const float4*)(fw + t * 4);
  float4 b4 = *(const float4*)(fb + t * 4);
  float4 x1;
  x1.x = (v.x - m) * rs * w4.x + b4.x;
  x1.y = (v.y - m) * rs * w4.y + b4.y;
  x1.z = (v.z - m) * rs * w4.z + b4.z;
  x1.w = (v.w - m) * rs * w4.w + b4.w;
  __syncthreads();
  float s2 = x1.x + x1.y + x1.z + x1.w;
  float ss2 = x1.x*x1.x + x1.y*x1.y + x1.z*x1.z + x1.w*x1.w;
  #pragma unroll
  for (int o = 32; o > 0; o >>= 1) { s2 += __shfl_xor(s2, o); ss2 += __shfl_xor(ss2, o); }
  if (lane == 0) { red[wv * 2] = s2; red[wv * 2 + 1] = ss2; }
  __syncthreads();
  float S2 = red[0] + red[2], SS2 = red[1] + red[3];
  float m2 = S2 * (1.f / D_), var2 = SS2 * (1.f / D_) - m2 * m2;
  float rs2 = rsqrtf(var2 + 1e-5f);
  float4 aw4 = *(const float4*)(aw + t * 4);
  float4 ab4 = *(const float4*)(ab + t * 4);
  float4 o;
  o.x = (x1.x - m2) * rs2 * aw4.x + ab4.x;
  o.y = (x1.y - m2) * rs2 * aw4.y + ab4.y;
  o.z = (x1.z - m2) * rs2 * aw4.z + ab4.z;
  o.w = (x1.w - m2) * rs2 * aw4.w + ab4.w;
  *(float4*)(out + (size_t)row * D_ + t * 4) = o;
  if (row == 0 && t < B_) {
    int q = ilens[t];
    out[outN + t] = (float)(q < L_ ? q : L_);
  }
}

extern "C" void kernel_launch(void* const* d_in, const int* in_sizes, int n_in,
                              void* d_out, int out_size, void* d_ws, size_t ws_size,
                              hipStream_t stream) {
  const float* xs     = (const float*)d_in[0];
  const int*   ilens  = (const int*)d_in[1];
  const float* norm_w = (const float*)d_in[2];
  const float* norm_b = (const float*)d_in[3];
  const float* in_w   = (const float*)d_in[4];
  const float* conv_w = (const float*)d_in[5];
  const float* conv_b = (const float*)d_in[6];
  const float* xp_w   = (const float*)d_in[7];
  const float* dt_w   = (const float*)d_in[8];
  const float* dt_b   = (const float*)d_in[9];
  const float* A_log  = (const float*)d_in[10];
  const float* Dp     = (const float*)d_in[11];
  const float* out_w  = (const float*)d_in[12];
  const float* nfw    = (const float*)d_in[13];
  const float* nfb    = (const float*)d_in[14];
  const float* afw    = (const float*)d_in[15];
  const float* afb    = (const float*)d_in[16];
  float* out = (float*)d_out;

  char* ws = (char*)d_ws;
  size_t off = 0;
  auto alloc = [&](size_t bytes) -> char* {
    char* p = ws + off;
    off += (bytes + 255) & ~(size_t)255;
    return p;
  };
  bf16*  inw_b  = (bf16*)alloc((size_t)NL_ * 2 * DI_ * D_ * 2);
  bf16*  outw_b = (bf16*)alloc((size_t)NL_ * D_ * DI_ * 2);
  bf16*  xpw_b  = (bf16*)alloc((size_t)NL_ * 128 * DI_ * 2);
  bf16*  dtw_b  = (bf16*)alloc((size_t)NL_ * DI_ * R_ * 2);
  float* an2b   = (float*)alloc((size_t)NL_ * DI_ * 4);
  float* ffb    = (float*)alloc((size_t)NL_ * DI_ * 4);
  float* an2f   = (float*)alloc((size_t)NL_ * S_ * DI_ * 4);
  float* resid  = (float*)alloc((size_t)BL_ * D_ * 4);
  bf16*  hn_b   = (bf16*)alloc((size_t)BL_ * D_ * 2);
  bf16*  xzb    = (bf16*)alloc((size_t)BL_ * 2 * DI_ * 2);
  bf16*  xcb    = (bf16*)alloc((size_t)BL_ * DI_ * 2);
  bf16*  xpart  = (bf16*)alloc((size_t)SKX * BL_ * 64 * 2);
  float* dbc    = (float*)alloc((size_t)BL_ * 64 * 4);
  bf16*  dbcb   = (bf16*)alloc((size_t)BL_ * 64 * 2);
  bf16*  dtb    = (bf16*)alloc((size_t)BL_ * DI_ * 2);
  float* sdt    = (float*)alloc((size_t)NC_ * BDI_ * 4);
  bf16*  qb     = (bf16*)alloc((size_t)S_ * NC_ * BDI_ * 2);
  bf16*  hini   = (bf16*)alloc((size_t)S_ * NC_ * BDI_ * 2);
  bf16*  yb     = (bf16*)alloc((size_t)BL_ * DI_ * 2);
  bf16*  opart  = (bf16*)alloc((size_t)SKO * BL_ * D_ * 2);
  if (off > ws_size) return;  // workspace too small — fail loudly via validation

  setup_k<<<4096, 256, 0, stream>>>(in_w, out_w, xp_w, dt_w, A_log,
                                    inw_b, outw_b, xpw_b, dtw_b, an2b, ffb, an2f);

  for (int i = 0; i < NL_; ++i) {
    addln_k<<<BL_, 128, 0, stream>>>(xs, (const u16*)opart, resid,
                                     norm_w + i * D_, norm_b + i * D_, hn_b, i == 0);
    dim3 g1(32, 16, 1);
    gemm_bt<<<g1, 256, 0, stream>>>(hn_b, D_, inw_b + (size_t)i * 2 * DI_ * D_, D_,
                                    xzb, nullptr, D_, 2 * DI_, BL_, 3);
    conv_silu_k<<<(BL_ * DI_ / 8) / 256, 256, 0, stream>>>(
        (const u16*)xzb, conv_w + i * DI_ * KC_, conv_b + i * DI_, xcb);
    dim3 g2(32, 1, SKX);
    gemm_bt<<<g2, 256, 0, stream>>>(xcb, DI_, xpw_b + (size_t)i * 128 * DI_, DI_,
                                    xpart, nullptr, DI_, 64, BL_, 1);
    redx_k<<<(BL_ * 64) / 256, 256, 0, stream>>>((const u16*)xpart, dbc, dbcb);
    dim3 g3(32, 8, 1);
    gemm_bt<<<g3, 256, 0, stream>>>(dbcb, 64, dtw_b + (size_t)i * DI_ * R_, R_,
                                    dtb, dt_b + i * DI_, R_, DI_, BL_, 2);
    scanA_k<<<(NC_ * B_ * DI_) / 256, 256, 0, stream>>>(
        (const u16*)dtb, (const u16*)xcb, dbc,
        an2b + i * DI_, ffb + i * DI_, A_log + (size_t)i * DI_ * S_, sdt, qb);
    scanB_k<<<(B_ * DI_ * S_) / 256, 256, 0, stream>>>(
        sdt, (const u16*)qb, an2f + (size_t)i * S_ * DI_, hini);
    scanC_k<<<(NC_ * B_ * DI_) / 256, 256, 0, stream>>>(
        (const u16*)dtb, (const u16*)xcb, dbc, A_log + (size_t)i * DI_ * S_,
        an2b + i * DI_, ffb + i * DI_, Dp + i * DI_,
        (const u16*)xzb, (const u16*)hini, yb);
    dim3 g4(32, 4, SKO);
    gemm_bt<<<g4, 256, 0, stream>>>(yb, DI_, outw_b + (size_t)i * D_ * DI_, DI_,
                                    opart, nullptr, DI_, D_, BL_, 1);
  }
  final_k<<<BL_, 128, 0, stream>>>((const u16*)opart, resid, nfw, nfb, afw, afb, ilens, out,
                                   out_size - B_);
}

// Round 13
// 721.818 us; speedup vs baseline: 1.1003x; 1.1003x over previous
//
#include <hip/hip_runtime.h>
#include <hip/hip_bf16.h>
#include <math.h>

#define D_   512
#define DI_  1024
#define S_   16
#define R_   32
#define KC_  4
#define NL_  6
#define B_   4
#define L_   1024
#define BL_  (B_*L_)
#define NC_  64
#define CL_  (L_/NC_)
#define BDI_ (B_*DI_)
#define LOG2E 1.44269504f
#define SKX  8
#define SKO  4

typedef __hip_bfloat16 bf16;
typedef __attribute__((ext_vector_type(8))) short bf16x8;
typedef __attribute__((ext_vector_type(4))) float f32x4;
typedef unsigned short u16;

// q / hini layout: [s][c][b*DI+d]  (fast axis d -> coalesced)
#define QIDX(s, c, bd) (((size_t)(s) * NC_ + (c)) * BDI_ + (bd))

__device__ __forceinline__ float b2f(u16 u) {
  union { unsigned int i; float f; } x; x.i = ((unsigned int)u) << 16; return x.f;
}

__device__ __forceinline__ float softplus_f(float v) {
  float e = __expf(-fabsf(v));
  return fmaxf(v, 0.f) + __logf(1.f + e);
}

__device__ __forceinline__ void gload16(const void* g, void* l) {
  __builtin_amdgcn_global_load_lds((const __attribute__((address_space(1))) void*)g,
                                   (__attribute__((address_space(3))) void*)l, 16, 0, 0);
}

// ---------------- one-shot setup: weight converts + A-table precompute ----------------
#define N1_ (NL_*2*DI_*D_)
#define N2_ (N1_ + NL_*D_*DI_)
#define N3_ (N2_ + NL_*128*DI_)
#define N4_ (N3_ + NL_*DI_)
__global__ void setup_k(const float* __restrict__ in_w, const float* __restrict__ out_w,
                        const float* __restrict__ xp_w, const float* __restrict__ A_log,
                        bf16* __restrict__ inw_b, bf16* __restrict__ outw_b,
                        bf16* __restrict__ xpw_b,
                        float* __restrict__ an2b, float* __restrict__ ff,
                        float* __restrict__ an2f) {
  for (int i = blockIdx.x * blockDim.x + threadIdx.x; i < N4_; i += gridDim.x * blockDim.x) {
    if (i < N1_) {
      inw_b[i] = __float2bfloat16(in_w[i]);
    } else if (i < N2_) {
      int j = i - N1_;
      outw_b[j] = __float2bfloat16(out_w[j]);
    } else if (i < N3_) {
      int j = i - N2_;
      int c = j & (DI_ - 1);
      int r = (j >> 10) & 127;
      int l = j >> 17;
      float v = (r < 64) ? xp_w[((size_t)l * 64 + r) * DI_ + c] : 0.f;
      xpw_b[j] = __float2bfloat16(v);
    } else {
      int j = i - N3_;                           // j = l*DI + d
      int d = j & (DI_ - 1);
      int l = j >> 10;
      float base = -expf(A_log[(size_t)j * S_]) * LOG2E;
      bool fast = true;
      #pragma unroll
      for (int s = 0; s < S_; ++s) {
        float a = -expf(A_log[(size_t)j * S_ + s]) * LOG2E;
        an2f[((size_t)l * S_ + s) * DI_ + d] = a;
        fast = fast && (fabsf(a - (float)(s + 1) * base) <= 1e-5f * fabsf(a));
      }
      an2b[j] = base;
      ff[j] = fast ? 1.f : 0.f;
    }
  }
}

// ---------------- residual add (+ bf16 split-K reduce) + LayerNorm -> bf16 ----------------
__global__ __launch_bounds__(128) void addln_k(
    const float* __restrict__ x0, const u16* __restrict__ parts,
    float* __restrict__ resid, const float* __restrict__ w, const float* __restrict__ b,
    bf16* __restrict__ hn, int first)
{
  __shared__ float red[4];
  const int row = blockIdx.x, t = threadIdx.x;
  const int lane = t & 63, wv = t >> 6;
  float4 v;
  if (first) {
    v = *(const float4*)(x0 + (size_t)row * D_ + t * 4);
  } else {
    const size_t ps = (size_t)BL_ * D_;
    const size_t o = (size_t)row * D_ + t * 4;
    v.x = 0.f; v.y = 0.f; v.z = 0.f; v.w = 0.f;
    #pragma unroll
    for (int p = 0; p < SKO; ++p) {
      ushort4 q = *(const ushort4*)(parts + p * ps + o);
      v.x += b2f(q.x); v.y += b2f(q.y); v.z += b2f(q.z); v.w += b2f(q.w);
    }
    float4 r = *(const float4*)(resid + o);
    v.x += r.x; v.y += r.y; v.z += r.z; v.w += r.w;
  }
  *(float4*)(resid + (size_t)row * D_ + t * 4) = v;
  float s = v.x + v.y + v.z + v.w;
  float ss = v.x*v.x + v.y*v.y + v.z*v.z + v.w*v.w;
  #pragma unroll
  for (int o = 32; o > 0; o >>= 1) { s += __shfl_xor(s, o); ss += __shfl_xor(ss, o); }
  if (lane == 0) { red[wv * 2] = s; red[wv * 2 + 1] = ss; }
  __syncthreads();
  float S = red[0] + red[2], SS = red[1] + red[3];
  float m = S * (1.f / D_), var = SS * (1.f / D_) - m * m;
  float rs = rsqrtf(var + 1e-5f);
  float4 w4 = *(const float4*)(w + t * 4);
  float4 b4 = *(const float4*)(b + t * 4);
  bf16* o = hn + (size_t)row * D_ + t * 4;
  o[0] = __float2bfloat16((v.x - m) * rs * w4.x + b4.x);
  o[1] = __float2bfloat16((v.y - m) * rs * w4.y + b4.y);
  o[2] = __float2bfloat16((v.z - m) * rs * w4.z + b4.z);
  o[3] = __float2bfloat16((v.w - m) * rs * w4.w + b4.w);
}

// ---------------- bf16 MFMA GEMM, C[m,n] = sum_k A[m,k]*B[n,k] ----------------
// Split-K via gridDim.z. epi: 1 = bf16 partial store [kz][M][Nact]; 3 = bf16 dense
__global__ __launch_bounds__(256) void gemm_bt(
    const bf16* __restrict__ A, int lda,
    const bf16* __restrict__ B, int ldb,
    bf16* __restrict__ Cb,
    int K, int Nact, int M, int epi)
{
  __shared__ __align__(16) bf16 As[128 * 32];
  __shared__ __align__(16) bf16 Bs[128 * 32];
  const int tid = threadIdx.x;
  const int wave = tid >> 6, lane = tid & 63;
  const int bm = blockIdx.x * 128, bn = blockIdx.y * 128;
  const int kz = blockIdx.z;
  const int Kc = K / gridDim.z;
  const int k0 = kz * Kc, k1 = k0 + Kc;
  const int wr = (wave >> 1) << 6, wc = (wave & 1) << 6;
  const int srow = lane >> 2, scg = lane & 3;
  const int rA = lane & 15, kq = (lane >> 4) << 3;
  f32x4 acc[4][4] = {};
  for (int kt = k0; kt < k1; kt += 32) {
    __syncthreads();
    #pragma unroll
    for (int p = 0; p < 2; ++p) {
      int chunk = wave * 2 + p;
      int row = (chunk << 4) + srow;
      gload16(A + (size_t)(bm + row) * lda + kt + scg * 8, &As[chunk * 512]);
      gload16(B + (size_t)(bn + row) * ldb + kt + scg * 8, &Bs[chunk * 512]);
    }
    __syncthreads();
    bf16x8 af[4], bq[4];
    #pragma unroll
    for (int m = 0; m < 4; ++m) af[m] = *(const bf16x8*)&As[(wr + m * 16 + rA) * 32 + kq];
    #pragma unroll
    for (int n = 0; n < 4; ++n) bq[n] = *(const bf16x8*)&Bs[(wc + n * 16 + rA) * 32 + kq];
    #pragma unroll
    for (int m = 0; m < 4; ++m)
      #pragma unroll
      for (int n = 0; n < 4; ++n)
        acc[m][n] = __builtin_amdgcn_mfma_f32_16x16x32_bf16(af[m], bq[n], acc[m][n], 0, 0, 0);
  }
  const int cr = (lane >> 4) << 2, cc = lane & 15;
  const size_t pbase = (epi == 1) ? (size_t)kz * M * Nact : 0;
  #pragma unroll
  for (int m = 0; m < 4; ++m)
    #pragma unroll
    for (int n = 0; n < 4; ++n) {
      int col = bn + wc + n * 16 + cc;
      if (col >= Nact) continue;
      #pragma unroll
      for (int j = 0; j < 4; ++j) {
        size_t row = (size_t)(bm + wr + m * 16 + cr + j);
        Cb[pbase + row * Nact + col] = __float2bfloat16(acc[m][n][j]);
      }
    }
}

// ---------------- causal conv (K=4) + SiLU, bf16 in/out, 8 chans/thread ----------------
__global__ __launch_bounds__(256) void conv_silu_k(
    const u16* __restrict__ xz, const float* __restrict__ cw, const float* __restrict__ cb,
    bf16* __restrict__ xcb)
{
  int g = blockIdx.x * 256 + threadIdx.x;     // BL*DI/8 threads
  int dq = g & (DI_ / 8 - 1);
  int bl = g >> 7;
  int l = bl & (L_ - 1), b = bl >> 10;
  int d = dq * 8;
  float a[8], wv[8][KC_];
  #pragma unroll
  for (int e = 0; e < 8; ++e) {
    float4 w4 = *(const float4*)(cw + (d + e) * KC_);
    wv[e][0] = w4.x; wv[e][1] = w4.y; wv[e][2] = w4.z; wv[e][3] = w4.w;
    a[e] = cb[d + e];
  }
  #pragma unroll
  for (int k = 0; k < KC_; ++k) {
    int lt = l + k - 3;
    if (lt < 0) continue;
    bf16x8 xv = *(const bf16x8*)(xz + (size_t)(b * L_ + lt) * (2 * DI_) + d);
    #pragma unroll
    for (int e = 0; e < 8; ++e) a[e] += b2f((u16)xv[e]) * wv[e][k];
  }
  bf16 o8[8];
  #pragma unroll
  for (int e = 0; e < 8; ++e) {
    float v = a[e] / (1.f + __expf(-a[e]));
    o8[e] = __float2bfloat16(v);
  }
  *(bf16x8*)(xcb + (size_t)bl * DI_ + d) = *(const bf16x8*)o8;
}

// ---------------- chunked selective scan (3 kernels), CL=16 ----------------
// fast path: dA[s] = E^(s+1), E = exp2(dt*an2b). Generic per-s fallback stays correct.

// pass A: inline split-K reduce of xpart (all 64 cols -> LDS; quarter-0 block writes
// cols 32..63 to dbcC f32 for scanC) + fused dt_proj(softplus) + local scan (h0=0)
__global__ __launch_bounds__(256) void scanA_k(
    const u16* __restrict__ x, const u16* __restrict__ xpart,
    const float* __restrict__ dtw, const float* __restrict__ dtbias,
    const float* __restrict__ A_log, const float* __restrict__ an2b,
    const float* __restrict__ ff, float* __restrict__ sumdt,
    bf16* __restrict__ q, bf16* __restrict__ dtb, float* __restrict__ dbcC)
{
  __shared__ float SM[CL_ * 64];                 // [row][col 0..63] of this chunk
  const int tid = threadIdx.x;
  int g = blockIdx.x * 256 + tid;                // NC*B*DI threads
  int d = g & (DI_ - 1);
  int cb = g >> 10;
  int b = cb & (B_ - 1);
  int c = cb >> 2;
  const int quarter = blockIdx.x & 3;            // 4 blocks share each (c,b)
  {
    const size_t ps = (size_t)BL_ * 64;
    for (int vi = 0; vi < 4; ++vi) {
      int idx = vi * 256 + tid;                  // CL*64 = 1024
      int row = idx >> 6, col = idx & 63;
      size_t rb = ((size_t)(b * L_ + c * CL_ + row)) * 64 + col;
      float v = 0.f;
      #pragma unroll
      for (int p = 0; p < SKX; ++p) v += b2f(xpart[p * ps + rb]);
      SM[idx] = v;
      if (quarter == 0 && col >= 32)
        dbcC[((size_t)(b * L_ + c * CL_ + row)) * 32 + (col - 32)] = v;
    }
  }
  float wv[R_];
  #pragma unroll
  for (int r = 0; r < R_; r += 4) {
    float4 w4 = *(const float4*)(dtw + (size_t)d * R_ + r);
    wv[r] = w4.x; wv[r + 1] = w4.y; wv[r + 2] = w4.z; wv[r + 3] = w4.w;
  }
  const float bias = dtbias[d];
  const float An2b = an2b[d];
  const bool fast = (ff[d] != 0.f);
  __syncthreads();
  float h[S_] = {};
  float sdt = 0.f;
  const size_t base = ((size_t)b * L_ + c * CL_) * DI_ + d;
  float cx = b2f(x[base]);
  float dtv;
  {
    float v = bias;
    #pragma unroll
    for (int r = 0; r < R_; r += 4) {
      float4 dv = *(const float4*)&SM[r];
      v += dv.x * wv[r] + dv.y * wv[r + 1] + dv.z * wv[r + 2] + dv.w * wv[r + 3];
    }
    dtv = softplus_f(v);
  }
  for (int i = 0; i < CL_; ++i) {
    const int ip = (i + 1 < CL_) ? i + 1 : i;
    float nx = b2f(x[base + (size_t)ip * DI_]);
    // next timestep's dt dot (issued early; finishes after h-update)
    float vn = bias;
    #pragma unroll
    for (int r = 0; r < R_; r += 4) {
      float4 dv = *(const float4*)&SM[ip * 64 + r];
      vn += dv.x * wv[r] + dv.y * wv[r + 1] + dv.z * wv[r + 2] + dv.w * wv[r + 3];
    }
    dtb[base + (size_t)i * DI_] = __float2bfloat16(dtv);
    sdt += dtv;
    float u = dtv * cx;
    float Bv[S_];
    *(float4*)&Bv[0]  = *(const float4*)&SM[i * 64 + 32];
    *(float4*)&Bv[4]  = *(const float4*)&SM[i * 64 + 36];
    *(float4*)&Bv[8]  = *(const float4*)&SM[i * 64 + 40];
    *(float4*)&Bv[12] = *(const float4*)&SM[i * 64 + 44];
    float da[S_];
    if (fast) {
      float E1 = exp2f(dtv * An2b);
      float E2 = E1 * E1;
      float E4 = E2 * E2;
      da[0] = E1; da[1] = E2; da[2] = E2 * E1; da[3] = E4;
      #pragma unroll
      for (int s = 4; s < S_; ++s) da[s] = da[s - 4] * E4;
    } else {
      #pragma unroll
      for (int s = 0; s < S_; ++s)
        da[s] = exp2f(dtv * (-expf(A_log[(size_t)d * S_ + s]) * LOG2E));
    }
    #pragma unroll
    for (int s = 0; s < S_; ++s) h[s] = da[s] * h[s] + u * Bv[s];
    dtv = softplus_f(vn);
    cx = nx;
  }
  int bd = b * DI_ + d;
  sumdt[(size_t)c * BDI_ + bd] = sdt;
  #pragma unroll
  for (int s = 0; s < S_; ++s) q[QIDX(s, c, bd)] = __float2bfloat16(h[s]);
}

// pass B: per (s,bd): propagate chunk boundary states (bf16 q/hi); an2f coalesced
__global__ __launch_bounds__(256) void scanB_k(
    const float* __restrict__ sumdt, const u16* __restrict__ q,
    const float* __restrict__ an2f, bf16* __restrict__ hi)
{
  int g = blockIdx.x * 256 + threadIdx.x;        // B*DI*S threads: g = s*BDI + bd
  int s = g >> 12;
  int bd = g & (BDI_ - 1);
  int d = bd & (DI_ - 1);
  float An2 = an2f[(size_t)s * DI_ + d];
  float h = 0.f;
  float sd = sumdt[bd];
  float qq = b2f(q[(size_t)s * NC_ * BDI_ + bd]);
  for (int c = 0; c < NC_; ++c) {
    float sdn = sd, qn = qq;
    if (c + 1 < NC_) {
      sdn = sumdt[(size_t)(c + 1) * BDI_ + bd];
      qn  = b2f(q[QIDX(s, c + 1, bd)]);
    }
    hi[QIDX(s, c, bd)] = __float2bfloat16(h);
    h = exp2f(An2 * sd) * h + qq;
    sd = sdn; qq = qn;
  }
}

// pass C: rescan with correct init; fuse y = (scan + x*Dp) * silu(z) -> bf16
// B/C rows read from dbcC (pre-reduced f32, 32 cols: [B(16)|C(16)])
__global__ __launch_bounds__(256) void scanC_k(
    const u16* __restrict__ dt, const u16* __restrict__ x, const float* __restrict__ dbcC,
    const float* __restrict__ A_log, const float* __restrict__ an2b,
    const float* __restrict__ ff, const float* __restrict__ Dp, const u16* __restrict__ xz,
    const u16* __restrict__ hi, bf16* __restrict__ y)
{
  __shared__ float BCS[CL_ * 32];                // B+C rows of this chunk
  const int tid = threadIdx.x;
  int g = blockIdx.x * 256 + tid;
  int d = g & (DI_ - 1);
  int cb = g >> 10;
  int b = cb & (B_ - 1);
  int c = cb >> 2;
  {
    int f = tid * 2;                             // 512 floats = CL*32
    int step = f >> 5, off = f & 31;
    float2 v = *(const float2*)(dbcC + ((size_t)(b * L_ + c * CL_ + step)) * 32 + off);
    BCS[f] = v.x; BCS[f + 1] = v.y;
  }
  const float An2b = an2b[d];
  const bool fast = (ff[d] != 0.f);
  int bd = b * DI_ + d;
  float h[S_];
  #pragma unroll
  for (int s = 0; s < S_; ++s) h[s] = b2f(hi[QIDX(s, c, bd)]);
  __syncthreads();
  float dpv = Dp[d];
  const size_t rid0 = (size_t)b * L_ + c * CL_;
  const size_t base = rid0 * DI_ + d;
  float cdt = b2f(dt[base]), cx = b2f(x[base]);
  float cz = b2f(xz[rid0 * (2 * DI_) + DI_ + d]);
  float Ecur = exp2f(cdt * An2b);
  for (int i = 0; i < CL_; ++i) {
    const int ip = (i + 1 < CL_) ? i + 1 : i;
    float ndt = b2f(dt[base + (size_t)ip * DI_]);
    float nx  = b2f(x[base + (size_t)ip * DI_]);
    float nz  = b2f(xz[(rid0 + ip) * (2 * DI_) + DI_ + d]);
    float Enext = exp2f(ndt * An2b);             // next boundary exp, issued early
    float u = cdt * cx;
    float Bv[S_], Cv[S_];
    *(float4*)&Bv[0]  = *(const float4*)&BCS[i * 32 + 0];
    *(float4*)&Bv[4]  = *(const float4*)&BCS[i * 32 + 4];
    *(float4*)&Bv[8]  = *(const float4*)&BCS[i * 32 + 8];
    *(float4*)&Bv[12] = *(const float4*)&BCS[i * 32 + 12];
    *(float4*)&Cv[0]  = *(const float4*)&BCS[i * 32 + 16];
    *(float4*)&Cv[4]  = *(const float4*)&BCS[i * 32 + 20];
    *(float4*)&Cv[8]  = *(const float4*)&BCS[i * 32 + 24];
    *(float4*)&Cv[12] = *(const float4*)&BCS[i * 32 + 28];
    float da[S_];
    if (fast) {
      float E1 = Ecur;
      float E2 = E1 * E1;
      float E4 = E2 * E2;
      da[0] = E1; da[1] = E2; da[2] = E2 * E1; da[3] = E4;
      #pragma unroll
      for (int s = 4; s < S_; ++s) da[s] = da[s - 4] * E4;
    } else {
      #pragma unroll
      for (int s = 0; s < S_; ++s)
        da[s] = exp2f(cdt * (-expf(A_log[(size_t)d * S_ + s]) * LOG2E));
    }
    float acc = 0.f;
    #pragma unroll
    for (int s = 0; s < S_; ++s) {
      h[s] = da[s] * h[s] + u * Bv[s];
      acc += h[s] * Cv[s];
    }
    acc += cx * dpv;
    acc *= cz / (1.f + __expf(-cz));
    y[(rid0 + i) * DI_ + d] = __float2bfloat16(acc);
    cdt = ndt; cx = nx; cz = nz; Ecur = Enext;
  }
}

// ---------------- final: reduce out partials + resid, LN(normf), LN(after), olens ----------------
__global__ __launch_bounds__(128) void final_k(
    const u16* __restrict__ parts, const float* __restrict__ res,
    const float* __restrict__ fw, const float* __restrict__ fb,
    const float* __restrict__ aw, const float* __restrict__ ab,
    const int* __restrict__ ilens, float* __restrict__ out, int outN)
{
  __shared__ float red[4];
  const int row = blockIdx.x, t = threadIdx.x;
  const int lane = t & 63, wv = t >> 6;
  const size_t ps = (size_t)BL_ * D_;
  const size_t o0 = (size_t)row * D_ + t * 4;
  float4 v; v.x = 0.f; v.y = 0.f; v.z = 0.f; v.w = 0.f;
  #pragma unroll
  for (int p = 0; p < SKO; ++p) {
    ushort4 q = *(const ushort4*)(parts + p * ps + o0);
    v.x += b2f(q.x); v.y += b2f(q.y); v.z += b2f(q.z); v.w += b2f(q.w);
  }
  float4 r = *(const float4*)(res + o0);
  v.x += r.x; v.y += r.y; v.z += r.z; v.w += r.w;
  float s = v.x + v.y + v.z + v.w;
  float ss = v.x*v.x + v.y*v.y + v.z*v.z + v.w*v.w;
  #pragma unroll
  for (int o = 32; o > 0; o >>= 1) { s += __shfl_xor(s, o); ss += __shfl_xor(ss, o); }
  if (lane == 0) { red[wv * 2] = s; red[wv * 2 + 1] = ss; }
  __syncthreads();
  float S = red[0] + red[2], SS = red[1] + red[3];
  float m = S * (1.f / D_), var = SS * (1.f / D_) - m * m;
  float rs = rsqrtf(var + 1e-5f);
  float4 w4 = *(const float4*)(fw + t * 4);
  float4 b4 = *(const float4*)(fb + t * 4);
  float4 x1;
  x1.x = (v.x - m) * rs * w4.x + b4.x;
  x1.y = (v.y - m) * rs * w4.y + b4.y;
  x1.z = (v.z - m) * rs * w4.z + b4.z;
  x1.w = (v.w - m) * rs * w4.w + b4.w;
  __syncthreads();
  float s2 = x1.x + x1.y + x1.z + x1.w;
  float ss2 = x1.x*x1.x + x1.y*x1.y + x1.z*x1.z + x1.w*x1.w;
  #pragma unroll
  for (int o = 32; o > 0; o >>= 1) { s2 += __shfl_xor(s2, o); ss2 += __shfl_xor(ss2, o); }
  if (lane == 0) { red[wv * 2] = s2; red[wv * 2 + 1] = ss2; }
  __syncthreads();
  float S2 = red[0] + red[2], SS2 = red[1] + red[3];
  float m2 = S2 * (1.f / D_), var2 = SS2 * (1.f / D_) - m2 * m2;
  float rs2 = rsqrtf(var2 + 1e-5f);
  float4 aw4 = *(const float4*)(aw + t * 4);
  float4 ab4 = *(const float4*)(ab + t * 4);
  float4 o;
  o.x = (x1.x - m2) * rs2 * aw4.x + ab4.x;
  o.y = (x1.y - m2) * rs2 * aw4.y + ab4.y;
  o.z = (x1.z - m2) * rs2 * aw4.z + ab4.z;
  o.w = (x1.w - m2) * rs2 * aw4.w + ab4.w;
  *(float4*)(out + (size_t)row * D_ + t * 4) = o;
  if (row == 0 && t < B_) {
    int q = ilens[t];
    out[outN + t] = (float)(q < L_ ? q : L_);
  }
}

extern "C" void kernel_launch(void* const* d_in, const int* in_sizes, int n_in,
                              void* d_out, int out_size, void* d_ws, size_t ws_size,
                              hipStream_t stream) {
  const float* xs     = (const float*)d_in[0];
  const int*   ilens  = (const int*)d_in[1];
  const float* norm_w = (const float*)d_in[2];
  const float* norm_b = (const float*)d_in[3];
  const float* in_w   = (const float*)d_in[4];
  const float* conv_w = (const float*)d_in[5];
  const float* conv_b = (const float*)d_in[6];
  const float* xp_w   = (const float*)d_in[7];
  const float* dt_w   = (const float*)d_in[8];
  const float* dt_b   = (const float*)d_in[9];
  const float* A_log  = (const float*)d_in[10];
  const float* Dp     = (const float*)d_in[11];
  const float* out_w  = (const float*)d_in[12];
  const float* nfw    = (const float*)d_in[13];
  const float* nfb    = (const float*)d_in[14];
  const float* afw    = (const float*)d_in[15];
  const float* afb    = (const float*)d_in[16];
  float* out = (float*)d_out;

  char* ws = (char*)d_ws;
  size_t off = 0;
  auto alloc = [&](size_t bytes) -> char* {
    char* p = ws + off;
    off += (bytes + 255) & ~(size_t)255;
    return p;
  };
  bf16*  inw_b  = (bf16*)alloc((size_t)NL_ * 2 * DI_ * D_ * 2);
  bf16*  outw_b = (bf16*)alloc((size_t)NL_ * D_ * DI_ * 2);
  bf16*  xpw_b  = (bf16*)alloc((size_t)NL_ * 128 * DI_ * 2);
  float* an2b   = (float*)alloc((size_t)NL_ * DI_ * 4);
  float* ffb    = (float*)alloc((size_t)NL_ * DI_ * 4);
  float* an2f   = (float*)alloc((size_t)NL_ * S_ * DI_ * 4);
  float* resid  = (float*)alloc((size_t)BL_ * D_ * 4);
  bf16*  hn_b   = (bf16*)alloc((size_t)BL_ * D_ * 2);
  bf16*  xzb    = (bf16*)alloc((size_t)BL_ * 2 * DI_ * 2);
  bf16*  xcb    = (bf16*)alloc((size_t)BL_ * DI_ * 2);
  bf16*  xpart  = (bf16*)alloc((size_t)SKX * BL_ * 64 * 2);
  float* dbcC   = (float*)alloc((size_t)BL_ * 32 * 4);
  bf16*  dtb    = (bf16*)alloc((size_t)BL_ * DI_ * 2);
  float* sdt    = (float*)alloc((size_t)NC_ * BDI_ * 4);
  bf16*  qb     = (bf16*)alloc((size_t)S_ * NC_ * BDI_ * 2);
  bf16*  hini   = (bf16*)alloc((size_t)S_ * NC_ * BDI_ * 2);
  bf16*  yb     = (bf16*)alloc((size_t)BL_ * DI_ * 2);
  bf16*  opart  = (bf16*)alloc((size_t)SKO * BL_ * D_ * 2);
  if (off > ws_size) return;  // workspace too small — fail loudly via validation

  setup_k<<<4096, 256, 0, stream>>>(in_w, out_w, xp_w, A_log,
                                    inw_b, outw_b, xpw_b, an2b, ffb, an2f);

  for (int i = 0; i < NL_; ++i) {
    addln_k<<<BL_, 128, 0, stream>>>(xs, (const u16*)opart, resid,
                                     norm_w + i * D_, norm_b + i * D_, hn_b, i == 0);
    dim3 g1(32, 16, 1);
    gemm_bt<<<g1, 256, 0, stream>>>(hn_b, D_, inw_b + (size_t)i * 2 * DI_ * D_, D_,
                                    xzb, D_, 2 * DI_, BL_, 3);
    conv_silu_k<<<(BL_ * DI_ / 8) / 256, 256, 0, stream>>>(
        (const u16*)xzb, conv_w + i * DI_ * KC_, conv_b + i * DI_, xcb);
    dim3 g2(32, 1, SKX);
    gemm_bt<<<g2, 256, 0, stream>>>(xcb, DI_, xpw_b + (size_t)i * 128 * DI_, DI_,
                                    xpart, DI_, 64, BL_, 1);
    scanA_k<<<(NC_ * B_ * DI_) / 256, 256, 0, stream>>>(
        (const u16*)xcb, (const u16*)xpart, dt_w + (size_t)i * DI_ * R_, dt_b + i * DI_,
        A_log + (size_t)i * DI_ * S_, an2b + i * DI_, ffb + i * DI_, sdt, qb, dtb, dbcC);
    scanB_k<<<(B_ * DI_ * S_) / 256, 256, 0, stream>>>(
        sdt, (const u16*)qb, an2f + (size_t)i * S_ * DI_, hini);
    scanC_k<<<(NC_ * B_ * DI_) / 256, 256, 0, stream>>>(
        (const u16*)dtb, (const u16*)xcb, dbcC, A_log + (size_t)i * DI_ * S_,
        an2b + i * DI_, ffb + i * DI_, Dp + i * DI_,
        (const u16*)xzb, (const u16*)hini, yb);
    dim3 g4(32, 4, SKO);
    gemm_bt<<<g4, 256, 0, stream>>>(yb, DI_, outw_b + (size_t)i * D_ * DI_, DI_,
                                    opart, DI_, D_, BL_, 1);
  }
  final_k<<<BL_, 128, 0, stream>>>((const u16*)opart, resid, nfw, nfb, afw, afb, ilens, out,
                                   out_size - B_);
}

// Round 14
// 717.253 us; speedup vs baseline: 1.1073x; 1.0064x over previous
//
#include <hip/hip_runtime.h>
#include <hip/hip_bf16.h>
#include <math.h>

#define D_   512
#define DI_  1024
#define S_   16
#define R_   32
#define KC_  4
#define NL_  6
#define B_   4
#define L_   1024
#define BL_  (B_*L_)
#define NC_  64
#define CL_  (L_/NC_)
#define BDI_ (B_*DI_)
#define LOG2E 1.44269504f
#define SKX  8
#define SKO  4

typedef __hip_bfloat16 bf16;
typedef __attribute__((ext_vector_type(8))) short bf16x8;
typedef __attribute__((ext_vector_type(4))) float f32x4;
typedef unsigned short u16;

// q / hini layout: [s][c][b*DI+d]  (fast axis d -> coalesced)
#define QIDX(s, c, bd) (((size_t)(s) * NC_ + (c)) * BDI_ + (bd))

__device__ __forceinline__ float b2f(u16 u) {
  union { unsigned int i; float f; } x; x.i = ((unsigned int)u) << 16; return x.f;
}

__device__ __forceinline__ u16 f2bu(float f) {
  bf16 h = __float2bfloat16(f);
  return *(u16*)&h;
}

__device__ __forceinline__ float softplus_f(float v) {
  float e = __expf(-fabsf(v));
  return fmaxf(v, 0.f) + __logf(1.f + e);
}

__device__ __forceinline__ void gload16(const void* g, void* l) {
  __builtin_amdgcn_global_load_lds((const __attribute__((address_space(1))) void*)g,
                                   (__attribute__((address_space(3))) void*)l, 16, 0, 0);
}

// ---------------- one-shot setup: weight converts + A-table precompute ----------------
#define N1_ (NL_*2*DI_*D_)
#define N2_ (N1_ + NL_*D_*DI_)
#define N3_ (N2_ + NL_*128*DI_)
#define N4_ (N3_ + NL_*DI_)
__global__ void setup_k(const float* __restrict__ in_w, const float* __restrict__ out_w,
                        const float* __restrict__ xp_w, const float* __restrict__ A_log,
                        bf16* __restrict__ inw_b, bf16* __restrict__ outw_b,
                        bf16* __restrict__ xpw_b,
                        float* __restrict__ an2b, float* __restrict__ ff,
                        float* __restrict__ an2f) {
  for (int i = blockIdx.x * blockDim.x + threadIdx.x; i < N4_; i += gridDim.x * blockDim.x) {
    if (i < N1_) {
      inw_b[i] = __float2bfloat16(in_w[i]);
    } else if (i < N2_) {
      int j = i - N1_;
      outw_b[j] = __float2bfloat16(out_w[j]);
    } else if (i < N3_) {
      int j = i - N2_;
      int c = j & (DI_ - 1);
      int r = (j >> 10) & 127;
      int l = j >> 17;
      float v = (r < 64) ? xp_w[((size_t)l * 64 + r) * DI_ + c] : 0.f;
      xpw_b[j] = __float2bfloat16(v);
    } else {
      int j = i - N3_;                           // j = l*DI + d
      int d = j & (DI_ - 1);
      int l = j >> 10;
      float base = -expf(A_log[(size_t)j * S_]) * LOG2E;
      bool fast = true;
      #pragma unroll
      for (int s = 0; s < S_; ++s) {
        float a = -expf(A_log[(size_t)j * S_ + s]) * LOG2E;
        an2f[((size_t)l * S_ + s) * DI_ + d] = a;
        fast = fast && (fabsf(a - (float)(s + 1) * base) <= 1e-5f * fabsf(a));
      }
      an2b[j] = base;
      ff[j] = fast ? 1.f : 0.f;
    }
  }
}

// ---------------- residual add (+ bf16 split-K reduce) + LayerNorm -> bf16 ----------------
// resid kept in bf16 (precision headroom is ~1000x; LN renormalizes per layer)
__global__ __launch_bounds__(128) void addln_k(
    const float* __restrict__ x0, const u16* __restrict__ parts,
    u16* __restrict__ resid, const float* __restrict__ w, const float* __restrict__ b,
    bf16* __restrict__ hn, int first)
{
  __shared__ float red[4];
  const int row = blockIdx.x, t = threadIdx.x;
  const int lane = t & 63, wv = t >> 6;
  const size_t o = (size_t)row * D_ + t * 4;
  float4 v;
  if (first) {
    v = *(const float4*)(x0 + o);
  } else {
    const size_t ps = (size_t)BL_ * D_;
    v.x = 0.f; v.y = 0.f; v.z = 0.f; v.w = 0.f;
    #pragma unroll
    for (int p = 0; p < SKO; ++p) {
      ushort4 q = *(const ushort4*)(parts + p * ps + o);
      v.x += b2f(q.x); v.y += b2f(q.y); v.z += b2f(q.z); v.w += b2f(q.w);
    }
    ushort4 r = *(const ushort4*)(resid + o);
    v.x += b2f(r.x); v.y += b2f(r.y); v.z += b2f(r.z); v.w += b2f(r.w);
  }
  {
    ushort4 rw;
    rw.x = f2bu(v.x); rw.y = f2bu(v.y); rw.z = f2bu(v.z); rw.w = f2bu(v.w);
    *(ushort4*)(resid + o) = rw;
  }
  float s = v.x + v.y + v.z + v.w;
  float ss = v.x*v.x + v.y*v.y + v.z*v.z + v.w*v.w;
  #pragma unroll
  for (int o2 = 32; o2 > 0; o2 >>= 1) { s += __shfl_xor(s, o2); ss += __shfl_xor(ss, o2); }
  if (lane == 0) { red[wv * 2] = s; red[wv * 2 + 1] = ss; }
  __syncthreads();
  float S = red[0] + red[2], SS = red[1] + red[3];
  float m = S * (1.f / D_), var = SS * (1.f / D_) - m * m;
  float rs = rsqrtf(var + 1e-5f);
  float4 w4 = *(const float4*)(w + t * 4);
  float4 b4 = *(const float4*)(b + t * 4);
  bf16* o8 = hn + o;
  o8[0] = __float2bfloat16((v.x - m) * rs * w4.x + b4.x);
  o8[1] = __float2bfloat16((v.y - m) * rs * w4.y + b4.y);
  o8[2] = __float2bfloat16((v.z - m) * rs * w4.z + b4.z);
  o8[3] = __float2bfloat16((v.w - m) * rs * w4.w + b4.w);
}

// ---------------- bf16 MFMA GEMM, C[m,n] = sum_k A[m,k]*B[n,k] ----------------
// Split-K via gridDim.z. epi: 1 = bf16 partial store [kz][M][Nact]; 3 = bf16 dense
__global__ __launch_bounds__(256) void gemm_bt(
    const bf16* __restrict__ A, int lda,
    const bf16* __restrict__ B, int ldb,
    bf16* __restrict__ Cb,
    int K, int Nact, int M, int epi)
{
  __shared__ __align__(16) bf16 As[128 * 32];
  __shared__ __align__(16) bf16 Bs[128 * 32];
  const int tid = threadIdx.x;
  const int wave = tid >> 6, lane = tid & 63;
  const int bm = blockIdx.x * 128, bn = blockIdx.y * 128;
  const int kz = blockIdx.z;
  const int Kc = K / gridDim.z;
  const int k0 = kz * Kc, k1 = k0 + Kc;
  const int wr = (wave >> 1) << 6, wc = (wave & 1) << 6;
  const int srow = lane >> 2, scg = lane & 3;
  const int rA = lane & 15, kq = (lane >> 4) << 3;
  f32x4 acc[4][4] = {};
  for (int kt = k0; kt < k1; kt += 32) {
    __syncthreads();
    #pragma unroll
    for (int p = 0; p < 2; ++p) {
      int chunk = wave * 2 + p;
      int row = (chunk << 4) + srow;
      gload16(A + (size_t)(bm + row) * lda + kt + scg * 8, &As[chunk * 512]);
      gload16(B + (size_t)(bn + row) * ldb + kt + scg * 8, &Bs[chunk * 512]);
    }
    __syncthreads();
    bf16x8 af[4], bq[4];
    #pragma unroll
    for (int m = 0; m < 4; ++m) af[m] = *(const bf16x8*)&As[(wr + m * 16 + rA) * 32 + kq];
    #pragma unroll
    for (int n = 0; n < 4; ++n) bq[n] = *(const bf16x8*)&Bs[(wc + n * 16 + rA) * 32 + kq];
    #pragma unroll
    for (int m = 0; m < 4; ++m)
      #pragma unroll
      for (int n = 0; n < 4; ++n)
        acc[m][n] = __builtin_amdgcn_mfma_f32_16x16x32_bf16(af[m], bq[n], acc[m][n], 0, 0, 0);
  }
  const int cr = (lane >> 4) << 2, cc = lane & 15;
  const size_t pbase = (epi == 1) ? (size_t)kz * M * Nact : 0;
  #pragma unroll
  for (int m = 0; m < 4; ++m)
    #pragma unroll
    for (int n = 0; n < 4; ++n) {
      int col = bn + wc + n * 16 + cc;
      if (col >= Nact) continue;
      #pragma unroll
      for (int j = 0; j < 4; ++j) {
        size_t row = (size_t)(bm + wr + m * 16 + cr + j);
        Cb[pbase + row * Nact + col] = __float2bfloat16(acc[m][n][j]);
      }
    }
}

// ---------------- causal conv (K=4) + SiLU, bf16 in/out, 8 chans/thread ----------------
__global__ __launch_bounds__(256) void conv_silu_k(
    const u16* __restrict__ xz, const float* __restrict__ cw, const float* __restrict__ cb,
    bf16* __restrict__ xcb)
{
  int g = blockIdx.x * 256 + threadIdx.x;     // BL*DI/8 threads
  int dq = g & (DI_ / 8 - 1);
  int bl = g >> 7;
  int l = bl & (L_ - 1), b = bl >> 10;
  int d = dq * 8;
  float a[8], wv[8][KC_];
  #pragma unroll
  for (int e = 0; e < 8; ++e) {
    float4 w4 = *(const float4*)(cw + (d + e) * KC_);
    wv[e][0] = w4.x; wv[e][1] = w4.y; wv[e][2] = w4.z; wv[e][3] = w4.w;
    a[e] = cb[d + e];
  }
  #pragma unroll
  for (int k = 0; k < KC_; ++k) {
    int lt = l + k - 3;
    if (lt < 0) continue;
    bf16x8 xv = *(const bf16x8*)(xz + (size_t)(b * L_ + lt) * (2 * DI_) + d);
    #pragma unroll
    for (int e = 0; e < 8; ++e) a[e] += b2f((u16)xv[e]) * wv[e][k];
  }
  bf16 o8[8];
  #pragma unroll
  for (int e = 0; e < 8; ++e) {
    float v = a[e] / (1.f + __expf(-a[e]));
    o8[e] = __float2bfloat16(v);
  }
  *(bf16x8*)(xcb + (size_t)bl * DI_ + d) = *(const bf16x8*)o8;
}

// ---------------- chunked selective scan (3 kernels), CL=16 ----------------
// fast path: dA[s] = E^(s+1), E = exp2(dt*an2b). Generic per-s fallback stays correct.

// pass A: inline split-K reduce of xpart cols 0..47 (dt_r|B) -> LDS; quarter-0 block
// additionally reduces cols 32..63 -> dbcC f32 for scanC. Fused dt_proj(softplus) + scan.
__global__ __launch_bounds__(256) void scanA_k(
    const u16* __restrict__ x, const u16* __restrict__ xpart,
    const float* __restrict__ dtw, const float* __restrict__ dtbias,
    const float* __restrict__ A_log, const float* __restrict__ an2b,
    const float* __restrict__ ff, float* __restrict__ sumdt,
    bf16* __restrict__ q, bf16* __restrict__ dtb, float* __restrict__ dbcC)
{
  __shared__ float SM[CL_ * 48];                 // [row][dt_r(32) | B(16)]
  const int tid = threadIdx.x;
  int g = blockIdx.x * 256 + tid;                // NC*B*DI threads
  int d = g & (DI_ - 1);
  int cb = g >> 10;
  int b = cb & (B_ - 1);
  int c = cb >> 2;
  const int quarter = blockIdx.x & 3;            // 4 blocks share each (c,b)
  {
    const size_t ps = (size_t)BL_ * 64;
    for (int idx = tid; idx < CL_ * 48; idx += 256) {   // 768 = 3/thread
      int row = idx / 48, col = idx - row * 48;
      size_t rb = ((size_t)(b * L_ + c * CL_ + row)) * 64 + col;
      float v = 0.f;
      #pragma unroll
      for (int p = 0; p < SKX; ++p) v += b2f(xpart[p * ps + rb]);
      SM[idx] = v;
    }
    if (quarter == 0) {
      for (int idx = tid; idx < CL_ * 32; idx += 256) { // 512 = 2/thread
        int row = idx >> 5, col = idx & 31;
        size_t rb = ((size_t)(b * L_ + c * CL_ + row)) * 64 + 32 + col;
        float v = 0.f;
        #pragma unroll
        for (int p = 0; p < SKX; ++p) v += b2f(xpart[p * ps + rb]);
        dbcC[((size_t)(b * L_ + c * CL_ + row)) * 32 + col] = v;
      }
    }
  }
  float wv[R_];
  #pragma unroll
  for (int r = 0; r < R_; r += 4) {
    float4 w4 = *(const float4*)(dtw + (size_t)d * R_ + r);
    wv[r] = w4.x; wv[r + 1] = w4.y; wv[r + 2] = w4.z; wv[r + 3] = w4.w;
  }
  const float bias = dtbias[d];
  const float An2b = an2b[d];
  const bool fast = (ff[d] != 0.f);
  __syncthreads();
  float h[S_] = {};
  float sdt = 0.f;
  const size_t base = ((size_t)b * L_ + c * CL_) * DI_ + d;
  float cx = b2f(x[base]);
  float dtv;
  {
    float v = bias;
    #pragma unroll
    for (int r = 0; r < R_; r += 4) {
      float4 dv = *(const float4*)&SM[r];
      v += dv.x * wv[r] + dv.y * wv[r + 1] + dv.z * wv[r + 2] + dv.w * wv[r + 3];
    }
    dtv = softplus_f(v);
  }
  for (int i = 0; i < CL_; ++i) {
    const int ip = (i + 1 < CL_) ? i + 1 : i;
    float nx = b2f(x[base + (size_t)ip * DI_]);
    // next timestep's dt dot (issued early; finishes after h-update)
    float vn = bias;
    #pragma unroll
    for (int r = 0; r < R_; r += 4) {
      float4 dv = *(const float4*)&SM[ip * 48 + r];
      vn += dv.x * wv[r] + dv.y * wv[r + 1] + dv.z * wv[r + 2] + dv.w * wv[r + 3];
    }
    dtb[base + (size_t)i * DI_] = __float2bfloat16(dtv);
    sdt += dtv;
    float u = dtv * cx;
    float Bv[S_];
    *(float4*)&Bv[0]  = *(const float4*)&SM[i * 48 + 32];
    *(float4*)&Bv[4]  = *(const float4*)&SM[i * 48 + 36];
    *(float4*)&Bv[8]  = *(const float4*)&SM[i * 48 + 40];
    *(float4*)&Bv[12] = *(const float4*)&SM[i * 48 + 44];
    float da[S_];
    if (fast) {
      float E1 = exp2f(dtv * An2b);
      float E2 = E1 * E1;
      float E4 = E2 * E2;
      da[0] = E1; da[1] = E2; da[2] = E2 * E1; da[3] = E4;
      #pragma unroll
      for (int s = 4; s < S_; ++s) da[s] = da[s - 4] * E4;
    } else {
      #pragma unroll
      for (int s = 0; s < S_; ++s)
        da[s] = exp2f(dtv * (-expf(A_log[(size_t)d * S_ + s]) * LOG2E));
    }
    #pragma unroll
    for (int s = 0; s < S_; ++s) h[s] = da[s] * h[s] + u * Bv[s];
    dtv = softplus_f(vn);
    cx = nx;
  }
  int bd = b * DI_ + d;
  sumdt[(size_t)c * BDI_ + bd] = sdt;
  #pragma unroll
  for (int s = 0; s < S_; ++s) q[QIDX(s, c, bd)] = __float2bfloat16(h[s]);
}

// pass B: per (s,bd): propagate chunk boundary states (bf16 q/hi); an2f coalesced
__global__ __launch_bounds__(256) void scanB_k(
    const float* __restrict__ sumdt, const u16* __restrict__ q,
    const float* __restrict__ an2f, bf16* __restrict__ hi)
{
  int g = blockIdx.x * 256 + threadIdx.x;        // B*DI*S threads: g = s*BDI + bd
  int s = g >> 12;
  int bd = g & (BDI_ - 1);
  int d = bd & (DI_ - 1);
  float An2 = an2f[(size_t)s * DI_ + d];
  float h = 0.f;
  float sd = sumdt[bd];
  float qq = b2f(q[(size_t)s * NC_ * BDI_ + bd]);
  for (int c = 0; c < NC_; ++c) {
    float sdn = sd, qn = qq;
    if (c + 1 < NC_) {
      sdn = sumdt[(size_t)(c + 1) * BDI_ + bd];
      qn  = b2f(q[QIDX(s, c + 1, bd)]);
    }
    hi[QIDX(s, c, bd)] = __float2bfloat16(h);
    h = exp2f(An2 * sd) * h + qq;
    sd = sdn; qq = qn;
  }
}

// pass C: rescan with correct init; fuse y = (scan + x*Dp) * silu(z) -> bf16
// B/C rows read from dbcC (pre-reduced f32, 32 cols: [B(16)|C(16)])
__global__ __launch_bounds__(256) void scanC_k(
    const u16* __restrict__ dt, const u16* __restrict__ x, const float* __restrict__ dbcC,
    const float* __restrict__ A_log, const float* __restrict__ an2b,
    const float* __restrict__ ff, const float* __restrict__ Dp, const u16* __restrict__ xz,
    const u16* __restrict__ hi, bf16* __restrict__ y)
{
  __shared__ float BCS[CL_ * 32];                // B+C rows of this chunk
  const int tid = threadIdx.x;
  int g = blockIdx.x * 256 + tid;
  int d = g & (DI_ - 1);
  int cb = g >> 10;
  int b = cb & (B_ - 1);
  int c = cb >> 2;
  {
    int f = tid * 2;                             // 512 floats = CL*32
    int step = f >> 5, off = f & 31;
    float2 v = *(const float2*)(dbcC + ((size_t)(b * L_ + c * CL_ + step)) * 32 + off);
    BCS[f] = v.x; BCS[f + 1] = v.y;
  }
  const float An2b = an2b[d];
  const bool fast = (ff[d] != 0.f);
  int bd = b * DI_ + d;
  float h[S_];
  #pragma unroll
  for (int s = 0; s < S_; ++s) h[s] = b2f(hi[QIDX(s, c, bd)]);
  __syncthreads();
  float dpv = Dp[d];
  const size_t rid0 = (size_t)b * L_ + c * CL_;
  const size_t base = rid0 * DI_ + d;
  float cdt = b2f(dt[base]), cx = b2f(x[base]);
  float cz = b2f(xz[rid0 * (2 * DI_) + DI_ + d]);
  float Ecur = exp2f(cdt * An2b);
  for (int i = 0; i < CL_; ++i) {
    const int ip = (i + 1 < CL_) ? i + 1 : i;
    float ndt = b2f(dt[base + (size_t)ip * DI_]);
    float nx  = b2f(x[base + (size_t)ip * DI_]);
    float nz  = b2f(xz[(rid0 + ip) * (2 * DI_) + DI_ + d]);
    float Enext = exp2f(ndt * An2b);             // next boundary exp, issued early
    float u = cdt * cx;
    float Bv[S_], Cv[S_];
    *(float4*)&Bv[0]  = *(const float4*)&BCS[i * 32 + 0];
    *(float4*)&Bv[4]  = *(const float4*)&BCS[i * 32 + 4];
    *(float4*)&Bv[8]  = *(const float4*)&BCS[i * 32 + 8];
    *(float4*)&Bv[12] = *(const float4*)&BCS[i * 32 + 12];
    *(float4*)&Cv[0]  = *(const float4*)&BCS[i * 32 + 16];
    *(float4*)&Cv[4]  = *(const float4*)&BCS[i * 32 + 20];
    *(float4*)&Cv[8]  = *(const float4*)&BCS[i * 32 + 24];
    *(float4*)&Cv[12] = *(const float4*)&BCS[i * 32 + 28];
    float da[S_];
    if (fast) {
      float E1 = Ecur;
      float E2 = E1 * E1;
      float E4 = E2 * E2;
      da[0] = E1; da[1] = E2; da[2] = E2 * E1; da[3] = E4;
      #pragma unroll
      for (int s = 4; s < S_; ++s) da[s] = da[s - 4] * E4;
    } else {
      #pragma unroll
      for (int s = 0; s < S_; ++s)
        da[s] = exp2f(cdt * (-expf(A_log[(size_t)d * S_ + s]) * LOG2E));
    }
    float acc = 0.f;
    #pragma unroll
    for (int s = 0; s < S_; ++s) {
      h[s] = da[s] * h[s] + u * Bv[s];
      acc += h[s] * Cv[s];
    }
    acc += cx * dpv;
    acc *= cz / (1.f + __expf(-cz));
    y[(rid0 + i) * DI_ + d] = __float2bfloat16(acc);
    cdt = ndt; cx = nx; cz = nz; Ecur = Enext;
  }
}

// ---------------- final: reduce out partials + resid(bf16), LN(normf), LN(after), olens ----------------
__global__ __launch_bounds__(128) void final_k(
    const u16* __restrict__ parts, const u16* __restrict__ res,
    const float* __restrict__ fw, const float* __restrict__ fb,
    const float* __restrict__ aw, const float* __restrict__ ab,
    const int* __restrict__ ilens, float* __restrict__ out, int outN)
{
  __shared__ float red[4];
  const int row = blockIdx.x, t = threadIdx.x;
  const int lane = t & 63, wv = t >> 6;
  const size_t ps = (size_t)BL_ * D_;
  const size_t o0 = (size_t)row * D_ + t * 4;
  float4 v; v.x = 0.f; v.y = 0.f; v.z = 0.f; v.w = 0.f;
  #pragma unroll
  for (int p = 0; p < SKO; ++p) {
    ushort4 q = *(const ushort4*)(parts + p * ps + o0);
    v.x += b2f(q.x); v.y += b2f(q.y); v.z += b2f(q.z); v.w += b2f(q.w);
  }
  ushort4 r = *(const ushort4*)(res + o0);
  v.x += b2f(r.x); v.y += b2f(r.y); v.z += b2f(r.z); v.w += b2f(r.w);
  float s = v.x + v.y + v.z + v.w;
  float ss = v.x*v.x + v.y*v.y + v.z*v.z + v.w*v.w;
  #pragma unroll
  for (int o = 32; o > 0; o >>= 1) { s += __shfl_xor(s, o); ss += __shfl_xor(ss, o); }
  if (lane == 0) { red[wv * 2] = s; red[wv * 2 + 1] = ss; }
  __syncthreads();
  float S = red[0] + red[2], SS = red[1] + red[3];
  float m = S * (1.f / D_), var = SS * (1.f / D_) - m * m;
  float rs = rsqrtf(var + 1e-5f);
  float4 w4 = *(const float4*)(fw + t * 4);
  float4 b4 = *(const float4*)(fb + t * 4);
  float4 x1;
  x1.x = (v.x - m) * rs * w4.x + b4.x;
  x1.y = (v.y - m) * rs * w4.y + b4.y;
  x1.z = (v.z - m) * rs * w4.z + b4.z;
  x1.w = (v.w - m) * rs * w4.w + b4.w;
  __syncthreads();
  float s2 = x1.x + x1.y + x1.z + x1.w;
  float ss2 = x1.x*x1.x + x1.y*x1.y + x1.z*x1.z + x1.w*x1.w;
  #pragma unroll
  for (int o = 32; o > 0; o >>= 1) { s2 += __shfl_xor(s2, o); ss2 += __shfl_xor(ss2, o); }
  if (lane == 0) { red[wv * 2] = s2; red[wv * 2 + 1] = ss2; }
  __syncthreads();
  float S2 = red[0] + red[2], SS2 = red[1] + red[3];
  float m2 = S2 * (1.f / D_), var2 = SS2 * (1.f / D_) - m2 * m2;
  float rs2 = rsqrtf(var2 + 1e-5f);
  float4 aw4 = *(const float4*)(aw + t * 4);
  float4 ab4 = *(const float4*)(ab + t * 4);
  float4 o;
  o.x = (x1.x - m2) * rs2 * aw4.x + ab4.x;
  o.y = (x1.y - m2) * rs2 * aw4.y + ab4.y;
  o.z = (x1.z - m2) * rs2 * aw4.z + ab4.z;
  o.w = (x1.w - m2) * rs2 * aw4.w + ab4.w;
  *(float4*)(out + (size_t)row * D_ + t * 4) = o;
  if (row == 0 && t < B_) {
    int q = ilens[t];
    out[outN + t] = (float)(q < L_ ? q : L_);
  }
}

extern "C" void kernel_launch(void* const* d_in, const int* in_sizes, int n_in,
                              void* d_out, int out_size, void* d_ws, size_t ws_size,
                              hipStream_t stream) {
  const float* xs     = (const float*)d_in[0];
  const int*   ilens  = (const int*)d_in[1];
  const float* norm_w = (const float*)d_in[2];
  const float* norm_b = (const float*)d_in[3];
  const float* in_w   = (const float*)d_in[4];
  const float* conv_w = (const float*)d_in[5];
  const float* conv_b = (const float*)d_in[6];
  const float* xp_w   = (const float*)d_in[7];
  const float* dt_w   = (const float*)d_in[8];
  const float* dt_b   = (const float*)d_in[9];
  const float* A_log  = (const float*)d_in[10];
  const float* Dp     = (const float*)d_in[11];
  const float* out_w  = (const float*)d_in[12];
  const float* nfw    = (const float*)d_in[13];
  const float* nfb    = (const float*)d_in[14];
  const float* afw    = (const float*)d_in[15];
  const float* afb    = (const float*)d_in[16];
  float* out = (float*)d_out;

  char* ws = (char*)d_ws;
  size_t off = 0;
  auto alloc = [&](size_t bytes) -> char* {
    char* p = ws + off;
    off += (bytes + 255) & ~(size_t)255;
    return p;
  };
  bf16*  inw_b  = (bf16*)alloc((size_t)NL_ * 2 * DI_ * D_ * 2);
  bf16*  outw_b = (bf16*)alloc((size_t)NL_ * D_ * DI_ * 2);
  bf16*  xpw_b  = (bf16*)alloc((size_t)NL_ * 128 * DI_ * 2);
  float* an2b   = (float*)alloc((size_t)NL_ * DI_ * 4);
  float* ffb    = (float*)alloc((size_t)NL_ * DI_ * 4);
  float* an2f   = (float*)alloc((size_t)NL_ * S_ * DI_ * 4);
  u16*   resid  = (u16*)alloc((size_t)BL_ * D_ * 2);
  bf16*  hn_b   = (bf16*)alloc((size_t)BL_ * D_ * 2);
  bf16*  xzb    = (bf16*)alloc((size_t)BL_ * 2 * DI_ * 2);
  bf16*  xcb    = (bf16*)alloc((size_t)BL_ * DI_ * 2);
  bf16*  xpart  = (bf16*)alloc((size_t)SKX * BL_ * 64 * 2);
  float* dbcC   = (float*)alloc((size_t)BL_ * 32 * 4);
  bf16*  dtb    = (bf16*)alloc((size_t)BL_ * DI_ * 2);
  float* sdt    = (float*)alloc((size_t)NC_ * BDI_ * 4);
  bf16*  qb     = (bf16*)alloc((size_t)S_ * NC_ * BDI_ * 2);
  bf16*  hini   = (bf16*)alloc((size_t)S_ * NC_ * BDI_ * 2);
  bf16*  yb     = (bf16*)alloc((size_t)BL_ * DI_ * 2);
  bf16*  opart  = (bf16*)alloc((size_t)SKO * BL_ * D_ * 2);
  if (off > ws_size) return;  // workspace too small — fail loudly via validation

  setup_k<<<4096, 256, 0, stream>>>(in_w, out_w, xp_w, A_log,
                                    inw_b, outw_b, xpw_b, an2b, ffb, an2f);

  for (int i = 0; i < NL_; ++i) {
    addln_k<<<BL_, 128, 0, stream>>>(xs, (const u16*)opart, resid,
                                     norm_w + i * D_, norm_b + i * D_, hn_b, i == 0);
    dim3 g1(32, 16, 1);
    gemm_bt<<<g1, 256, 0, stream>>>(hn_b, D_, inw_b + (size_t)i * 2 * DI_ * D_, D_,
                                    xzb, D_, 2 * DI_, BL_, 3);
    conv_silu_k<<<(BL_ * DI_ / 8) / 256, 256, 0, stream>>>(
        (const u16*)xzb, conv_w + i * DI_ * KC_, conv_b + i * DI_, xcb);
    dim3 g2(32, 1, SKX);
    gemm_bt<<<g2, 256, 0, stream>>>(xcb, DI_, xpw_b + (size_t)i * 128 * DI_, DI_,
                                    xpart, DI_, 64, BL_, 1);
    scanA_k<<<(NC_ * B_ * DI_) / 256, 256, 0, stream>>>(
        (const u16*)xcb, (const u16*)xpart, dt_w + (size_t)i * DI_ * R_, dt_b + i * DI_,
        A_log + (size_t)i * DI_ * S_, an2b + i * DI_, ffb + i * DI_, sdt, qb, dtb, dbcC);
    scanB_k<<<(B_ * DI_ * S_) / 256, 256, 0, stream>>>(
        sdt, (const u16*)qb, an2f + (size_t)i * S_ * DI_, hini);
    scanC_k<<<(NC_ * B_ * DI_) / 256, 256, 0, stream>>>(
        (const u16*)dtb, (const u16*)xcb, dbcC, A_log + (size_t)i * DI_ * S_,
        an2b + i * DI_, ffb + i * DI_, Dp + i * DI_,
        (const u16*)xzb, (const u16*)hini, yb);
    dim3 g4(32, 4, SKO);
    gemm_bt<<<g4, 256, 0, stream>>>(yb, DI_, outw_b + (size_t)i * D_ * DI_, DI_,
                                    opart, DI_, D_, BL_, 1);
  }
  final_k<<<BL_, 128, 0, stream>>>((const u16*)opart, resid, nfw, nfb, afw, afb, ilens, out,
                                   out_size - B_);
}